// Round 4
// baseline (99.972 us; speedup 1.0000x reference)
//
#include <hip/hip_runtime.h>

// ChamferLoss: B=4, N=M=8192, D=3, fp32.
// loss = mean_b[ mean(pred2gt) + mean(gt2pred) + max(pred2gt) ]
// R4: test LDS-pipe-saturation theory. R2/R3 stuck at 53% of VALU peak at the
// same VALU:LDS issue ratio (56 VALU : 2 ds_read_b128 per wave-iter) -> PPT=16
// doubles the ratio (112:2). atomicMin-fused partial combine (pmin 256 KB,
// 0xFF memset = +inf sentinel for uint-min of nonneg floats). 3 graph nodes.

#define BATCH   4
#define NPTS    8192
#define SLICES  64
#define MS      (NPTS / SLICES)     // 128 y-points per slice
#define PPT     16                  // x-points per thread (register tile)
#define TPB     256
#define CHUNK   (TPB * PPT)         // 4096 x-points per block
#define NCHUNKS (NPTS / CHUNK)      // 2

__global__ __launch_bounds__(TPB, 4)   // cap VGPR <=128: keep 4 waves/SIMD
void nn_fused(const float* __restrict__ pred,
              const float* __restrict__ gt,
              unsigned int* __restrict__ pmin) {
    const int c  = blockIdx.x;       // x chunk
    const int s  = blockIdx.y;       // y slice
    const int bd = blockIdx.z;       // b*2 + dir
    const int b  = bd >> 1;
    const int dir = bd & 1;
    const float* x = (dir ? gt : pred) + (size_t)b * NPTS * 3;
    const float* y = (dir ? pred : gt) + (size_t)b * NPTS * 3;

    __shared__ float4 ys[MS];        // {yx, yy, yz, y2}  (2 KB)
    const int t = threadIdx.x;
    if (t < MS) {
        const float yx = y[(s * MS + t) * 3 + 0];
        const float yy = y[(s * MS + t) * 3 + 1];
        const float yz = y[(s * MS + t) * 3 + 2];
        ys[t] = make_float4(yx, yy, yz, yx * yx + yy * yy + yz * yz);
    }
    __syncthreads();

    // px = -2x so e_j = y2 + px.y ; d_j = x2 + min_j e_j (x2 hoisted).
    float px[PPT], py[PPT], pz[PPT], x2[PPT], emin[PPT];
    #pragma unroll
    for (int k = 0; k < PPT; ++k) {
        const int p = c * CHUNK + k * TPB + t;
        const float xx = x[p * 3 + 0];
        const float xy = x[p * 3 + 1];
        const float xz = x[p * 3 + 2];
        x2[k] = xx * xx + xy * xy + xz * xz;
        px[k] = -2.f * xx;
        py[k] = -2.f * xy;
        pz[k] = -2.f * xz;
        emin[k] = 3.4e38f;
    }

    // Per 2-y iter per wave: 112 VALU instr vs 2 ds_read_b128 (was 56:2).
    for (int j = 0; j < MS; j += 2) {
        const float4 q0 = ys[j];
        const float4 q1 = ys[j + 1];
        #pragma unroll
        for (int k = 0; k < PPT; ++k) {
            float e0 = fmaf(pz[k], q0.z, fmaf(py[k], q0.y, fmaf(px[k], q0.x, q0.w)));
            float e1 = fmaf(pz[k], q1.z, fmaf(py[k], q1.y, fmaf(px[k], q1.x, q1.w)));
            emin[k] = fminf(emin[k], fminf(e0, e1));   // -> v_min3_f32
        }
    }

    unsigned int* o = pmin + (size_t)bd * NPTS + c * CHUNK;
    #pragma unroll
    for (int k = 0; k < PPT; ++k) {
        const float d = fmaxf(emin[k] + x2[k], 0.f);   // sqdist >= 0
        atomicMin(&o[k * TPB + t], __float_as_uint(d));
    }
}

// One 1024-thread block: 128 threads per bd; sum + max per bd; write out[0].
__global__ __launch_bounds__(1024)
void reduce_all(const unsigned int* __restrict__ pmin,
                float* __restrict__ out) {
    const int t  = threadIdx.x;
    const int bd = t >> 7;              // 0..7
    const int l  = t & 127;
    const unsigned int* base = pmin + (size_t)bd * NPTS;
    float sum = 0.f, mx = -1.f;
    #pragma unroll
    for (int i = 0; i < NPTS / 128; ++i) {
        const float f = __uint_as_float(base[i * 128 + l]);
        sum += f;
        mx = fmaxf(mx, f);
    }
    // threads of one bd occupy exactly waves 2bd, 2bd+1 -> per-wave reduce.
    #pragma unroll
    for (int off = 32; off; off >>= 1) {
        sum += __shfl_down(sum, off, 64);
        mx = fmaxf(mx, __shfl_down(mx, off, 64));
    }
    __shared__ float ss[16], sm[16];
    if ((t & 63) == 0) { ss[t >> 6] = sum; sm[t >> 6] = mx; }
    __syncthreads();
    if (t == 0) {
        float acc = 0.f;
        #pragma unroll
        for (int d = 0; d < 8; ++d) {
            const float S = ss[2 * d] + ss[2 * d + 1];
            const float M = fmaxf(sm[2 * d], sm[2 * d + 1]);
            // even bd (pred2gt): mean + max ; odd bd (gt2pred): mean only.
            acc += S * (1.f / NPTS) + ((d & 1) ? 0.f : M);
        }
        out[0] = acc * (1.f / BATCH);
    }
}

extern "C" void kernel_launch(void* const* d_in, const int* in_sizes, int n_in,
                              void* d_out, int out_size, void* d_ws, size_t ws_size,
                              hipStream_t stream) {
    const float* pred = (const float*)d_in[0];
    const float* gt   = (const float*)d_in[1];

    unsigned int* pmin = (unsigned int*)d_ws;   // 2*B*NPTS uints = 256 KB

    hipMemsetAsync(pmin, 0xFF, (size_t)2 * BATCH * NPTS * 4, stream);  // +inf sentinel

    dim3 g1(NCHUNKS, SLICES, 2 * BATCH);   // 2 x 64 x 8 = 1024 blocks (4/CU)
    nn_fused<<<g1, TPB, 0, stream>>>(pred, gt, pmin);
    reduce_all<<<dim3(1), 1024, 0, stream>>>(pmin, (float*)d_out);
}